// Round 1
// baseline (1458.516 us; speedup 1.0000x reference)
//
#include <hip/hip_runtime.h>
#include <cstdint>
#include <cstddef>

// ---- constants ----
#define Bz 8
#define Lz 1024
#define Dz 512
#define Hz 8
#define NLz 6
#define DFz 2048
#define Mz (Bz*Lz)          // 8192 rows

typedef short bf16x8 __attribute__((ext_vector_type(8)));
typedef float f32x4  __attribute__((ext_vector_type(4)));

__device__ __forceinline__ short f2bf(float f) {
    unsigned u = __builtin_bit_cast(unsigned, f);
    u = (u + 0x7fff + ((u >> 16) & 1)) >> 16;
    return (short)u;
}

#define GLD16(gp, lp) __builtin_amdgcn_global_load_lds( \
    (const __attribute__((address_space(1))) void*)(gp), \
    (__attribute__((address_space(3))) void*)(lp), 16, 0, 0)

// ---------------- pos-emb add:  y = x + PE  ----------------
__global__ __launch_bounds__(256) void posadd_kernel(const float* __restrict__ x,
                                                     float* __restrict__ y) {
    int idx = blockIdx.x * 256 + threadIdx.x;       // < B*L*D
    int d   = idx & (Dz - 1);
    int pos = (idx >> 9) & (Lz - 1);
    int i2  = (d < Dz/2) ? d : d - Dz/2;
    float inv = __expf(-0.03597789207f * (float)i2);   // 10000^(-2i/D)
    float a = (float)pos * inv;
    float pe = (d < Dz/2) ? sinf(a) : cosf(a);
    y[idx] = x[idx] + pe;
}

// ---------------- LayerNorm (f32 in, bf16 out), one row per block ----------------
__global__ __launch_bounds__(256) void ln_kernel(const float* __restrict__ x,
                                                 const float* __restrict__ g,
                                                 const float* __restrict__ b,
                                                 short* __restrict__ out) {
    int row = blockIdx.x;
    int t = threadIdx.x;
    const float* xr = x + (size_t)row * Dz;
    float v0 = xr[t], v1 = xr[t + 256];
    float s = v0 + v1;
    #pragma unroll
    for (int off = 32; off; off >>= 1) s += __shfl_xor(s, off, 64);
    __shared__ float red[4];
    int w = t >> 6, l = t & 63;
    if (l == 0) red[w] = s;
    __syncthreads();
    float m = (red[0] + red[1] + red[2] + red[3]) * (1.0f / Dz);
    float d0 = v0 - m, d1 = v1 - m;
    float s2 = d0 * d0 + d1 * d1;
    #pragma unroll
    for (int off = 32; off; off >>= 1) s2 += __shfl_xor(s2, off, 64);
    __syncthreads();
    if (l == 0) red[w] = s2;
    __syncthreads();
    float var = (red[0] + red[1] + red[2] + red[3]) * (1.0f / Dz);
    float rs = rsqrtf(var + 1e-3f);
    out[(size_t)row * Dz + t]       = f2bf(d0 * rs * g[t] + b[t]);
    out[(size_t)row * Dz + t + 256] = f2bf(d1 * rs * g[t + 256] + b[t + 256]);
}

// ---------------- weight transpose + cast: dst[n][k] = bf16(src[k][n]), batched over layers -------
__global__ __launch_bounds__(256) void transpose_bf16_kernel(const float* __restrict__ src,
                                                             short* __restrict__ dst,
                                                             int K, int N,
                                                             long srcLS, long dstLS, int rowOff) {
    __shared__ float tile[32][33];
    int tx = threadIdx.x & 31, ty = threadIdx.x >> 5;
    int bx = blockIdx.x, by = blockIdx.y, z = blockIdx.z;
    const float* s = src + (size_t)z * srcLS;
    short* d = dst + (size_t)z * dstLS;
    #pragma unroll
    for (int i = 0; i < 4; i++)
        tile[ty + i * 8][tx] = s[(size_t)(by * 32 + ty + i * 8) * N + bx * 32 + tx];
    __syncthreads();
    #pragma unroll
    for (int i = 0; i < 4; i++)
        d[(size_t)(rowOff + bx * 32 + ty + i * 8) * K + by * 32 + tx] = f2bf(tile[tx][ty + i * 8]);
}

// ---------------- GEMM: C[M,N] = A[M,K] * W[K,N], W given transposed (Bt[N][K]), bf16 in, f32 acc
// MODE 0: out bf16 (no bias)            -> outb
// MODE 1: outf[idx] += acc              (residual in-place, f32)
// MODE 2: out bf16 = relu(acc + bias)   -> outb
// MODE 3: outf[idx] += acc + bias       (residual in-place, f32)
template<int MODE>
__global__ __launch_bounds__(256, 2) void gemm_bt(const short* __restrict__ A,
                                                  const short* __restrict__ Bt,
                                                  short* __restrict__ outb,
                                                  float* __restrict__ outf,
                                                  const float* __restrict__ bias,
                                                  int M, int N, int K) {
    __shared__ __attribute__((aligned(16))) short As[128 * 32];
    __shared__ __attribute__((aligned(16))) short Bs[128 * 32];
    int t = threadIdx.x;
    int m0 = blockIdx.x * 128, n0 = blockIdx.y * 128;
    int w = t >> 6, l = t & 63;
    int wm = (w >> 1) * 64, wn = (w & 1) * 64;
    int lr = l & 15, lq = l >> 4;
    f32x4 acc[4][4] = {};
    int e0 = t, e1 = t + 256;
    int ra0 = e0 >> 2, ca0 = (e0 & 3) * 8;
    int ra1 = e1 >> 2, ca1 = (e1 & 3) * 8;
    for (int kk = 0; kk < K; kk += 32) {
        GLD16(A + (size_t)(m0 + ra0) * K + kk + ca0, As + e0 * 8);
        GLD16(A + (size_t)(m0 + ra1) * K + kk + ca1, As + e1 * 8);
        GLD16(Bt + (size_t)(n0 + ra0) * K + kk + ca0, Bs + e0 * 8);
        GLD16(Bt + (size_t)(n0 + ra1) * K + kk + ca1, Bs + e1 * 8);
        __syncthreads();
        bf16x8 af[4], bfr[4];
        #pragma unroll
        for (int i = 0; i < 4; i++) af[i]  = *(const bf16x8*)(As + (wm + i * 16 + lr) * 32 + lq * 8);
        #pragma unroll
        for (int i = 0; i < 4; i++) bfr[i] = *(const bf16x8*)(Bs + (wn + i * 16 + lr) * 32 + lq * 8);
        #pragma unroll
        for (int mi = 0; mi < 4; mi++)
            #pragma unroll
            for (int ni = 0; ni < 4; ni++)
                acc[mi][ni] = __builtin_amdgcn_mfma_f32_16x16x32_bf16(af[mi], bfr[ni], acc[mi][ni], 0, 0, 0);
        __syncthreads();
    }
    #pragma unroll
    for (int mi = 0; mi < 4; mi++)
        #pragma unroll
        for (int ni = 0; ni < 4; ni++) {
            int col = n0 + wn + ni * 16 + lr;
            float bv = (MODE == 2 || MODE == 3) ? bias[col] : 0.0f;
            #pragma unroll
            for (int r = 0; r < 4; r++) {
                int row = m0 + wm + mi * 16 + lq * 4 + r;
                size_t idx = (size_t)row * N + col;
                float v = acc[mi][ni][r];
                if (MODE == 0)      outb[idx] = f2bf(v);
                else if (MODE == 1) outf[idx] += v;
                else if (MODE == 2) outb[idx] = f2bf(fmaxf(v + bv, 0.0f));
                else                outf[idx] += v + bv;
            }
        }
}

// ---------------- fused attention (flash-style, online softmax) ----------------
// qkv: [M][1536] bf16  (q | k | v, each [.. ][h*64+d]);  o: [M][512] bf16
__global__ __launch_bounds__(256) void attn_kernel(const short* __restrict__ qkv,
                                                   const int* __restrict__ lengths,
                                                   short* __restrict__ o) {
    int qt = blockIdx.x;            // q-tile of 64 rows
    int bh = blockIdx.y;
    int b = bh >> 3, h = bh & 7;
    int len = lengths[b];
    int t = threadIdx.x, w = t >> 6, l = t & 63;
    int lr = l & 15, lq = l >> 4;
    __shared__ __attribute__((aligned(16))) short Ks[32 * 64];
    __shared__ __attribute__((aligned(16))) short Vt[64 * 40];
    __shared__ __attribute__((aligned(16))) short Ps[4][16 * 40];
    int qbase = qt * 64 + w * 16;
    const short* qrow = qkv + (size_t)(b * Lz + qbase + lr) * 1536 + h * 64 + lq * 8;
    bf16x8 qf0 = *(const bf16x8*)(qrow);
    bf16x8 qf1 = *(const bf16x8*)(qrow + 32);
    float mrun[4] = {-3e38f, -3e38f, -3e38f, -3e38f};
    float lrun[4] = {0.f, 0.f, 0.f, 0.f};
    f32x4 oacc[4] = {};
    const float scale = 0.125f;     // 1/sqrt(64)
    for (int k0 = 0; k0 < len; k0 += 32) {
        {   // stage K tile [32][64]
            int kp = t >> 3, seg = (t & 7) * 8;
            *(uint4*)(Ks + kp * 64 + seg) =
                *(const uint4*)(qkv + (size_t)(b * Lz + k0 + kp) * 1536 + 512 + h * 64 + seg);
            // stage V^T tile [64][40-padded 32]
            int kp2 = t & 31, dbase = (t >> 5) * 8;
            union { uint4 u; short s[8]; } vv;
            vv.u = *(const uint4*)(qkv + (size_t)(b * Lz + k0 + kp2) * 1536 + 1024 + h * 64 + dbase);
            #pragma unroll
            for (int i = 0; i < 8; i++) Vt[(dbase + i) * 40 + kp2] = vv.s[i];
        }
        __syncthreads();
        f32x4 sacc[2] = {};
        #pragma unroll
        for (int kt = 0; kt < 2; kt++) {
            bf16x8 kf0 = *(const bf16x8*)(Ks + (kt * 16 + lr) * 64 + lq * 8);
            bf16x8 kf1 = *(const bf16x8*)(Ks + (kt * 16 + lr) * 64 + 32 + lq * 8);
            sacc[kt] = __builtin_amdgcn_mfma_f32_16x16x32_bf16(qf0, kf0, sacc[kt], 0, 0, 0);
            sacc[kt] = __builtin_amdgcn_mfma_f32_16x16x32_bf16(qf1, kf1, sacc[kt], 0, 0, 0);
        }
        float p[2][4];
        #pragma unroll
        for (int r = 0; r < 4; r++) {
            float s0 = sacc[0][r] * scale + ((k0 + lr) < len ? 0.0f : -1e9f);
            float s1 = sacc[1][r] * scale + ((k0 + 16 + lr) < len ? 0.0f : -1e9f);
            float mx = fmaxf(s0, s1);
            #pragma unroll
            for (int off = 1; off < 16; off <<= 1) mx = fmaxf(mx, __shfl_xor(mx, off, 64));
            float mnew = fmaxf(mrun[r], mx);
            float alpha = __expf(mrun[r] - mnew);
            float p0 = __expf(s0 - mnew);
            float p1 = __expf(s1 - mnew);
            float ps = p0 + p1;
            #pragma unroll
            for (int off = 1; off < 16; off <<= 1) ps += __shfl_xor(ps, off, 64);
            lrun[r] = lrun[r] * alpha + ps;
            mrun[r] = mnew;
            #pragma unroll
            for (int ni = 0; ni < 4; ni++) oacc[ni][r] *= alpha;
            p[0][r] = p0; p[1][r] = p1;
        }
        // P -> LDS (wave-private), then re-read as MFMA A-fragment
        short* Pw = &Ps[w][0];
        #pragma unroll
        for (int kt = 0; kt < 2; kt++)
            #pragma unroll
            for (int r = 0; r < 4; r++)
                Pw[(lq * 4 + r) * 40 + kt * 16 + lr] = f2bf(p[kt][r]);
        bf16x8 pf = *(const bf16x8*)(Pw + lr * 40 + lq * 8);
        #pragma unroll
        for (int ni = 0; ni < 4; ni++) {
            bf16x8 vf = *(const bf16x8*)(Vt + (ni * 16 + lr) * 40 + lq * 8);
            oacc[ni] = __builtin_amdgcn_mfma_f32_16x16x32_bf16(pf, vf, oacc[ni], 0, 0, 0);
        }
        __syncthreads();
    }
    float inv_[4];
    #pragma unroll
    for (int r = 0; r < 4; r++) inv_[r] = 1.0f / lrun[r];
    #pragma unroll
    for (int ni = 0; ni < 4; ni++)
        #pragma unroll
        for (int r = 0; r < 4; r++) {
            int q = qbase + lq * 4 + r;
            o[(size_t)(b * Lz + q) * Dz + h * 64 + ni * 16 + lr] = f2bf(oacc[ni][r] * inv_[r]);
        }
}

extern "C" void kernel_launch(void* const* d_in, const int* in_sizes, int n_in,
                              void* d_out, int out_size, void* d_ws, size_t ws_size,
                              hipStream_t stream) {
    const float* x_in    = (const float*)d_in[0];
    const int*   lengths = (const int*)d_in[1];
    const float* Wq   = (const float*)d_in[2];
    const float* Wk   = (const float*)d_in[3];
    const float* Wv   = (const float*)d_in[4];
    const float* Wo   = (const float*)d_in[5];
    const float* ln1g = (const float*)d_in[6];
    const float* ln1b = (const float*)d_in[7];
    const float* ln2g = (const float*)d_in[8];
    const float* ln2b = (const float*)d_in[9];
    const float* w1   = (const float*)d_in[10];
    const float* b1   = (const float*)d_in[11];
    const float* w2   = (const float*)d_in[12];
    const float* b2   = (const float*)d_in[13];

    size_t off = 0;
    auto alloc = [&](size_t bytes) {
        void* p = (char*)d_ws + off;
        off += (bytes + 255) & ~(size_t)255;
        return p;
    };
    float* x_work = (float*)alloc((size_t)Mz * Dz * 4);
    short* hbuf   = (short*)alloc((size_t)Mz * Dz * 2);        // LN out / attention out
    short* qkvb   = (short*)alloc((size_t)Mz * 1536 * 2);
    short* f1b    = (short*)alloc((size_t)Mz * DFz * 2);
    short* wqkvT  = (short*)alloc((size_t)NLz * 1536 * Dz * 2);
    short* woT    = (short*)alloc((size_t)NLz * Dz * Dz * 2);
    short* w1T    = (short*)alloc((size_t)NLz * DFz * Dz * 2);
    short* w2T    = (short*)alloc((size_t)NLz * Dz * DFz * 2);

    dim3 tb(256);
    // weight transposes (per call; same work every call)
    transpose_bf16_kernel<<<dim3(16, 16, NLz), tb, 0, stream>>>(Wq, wqkvT, Dz, Dz, (long)Dz*Dz, (long)1536*Dz, 0);
    transpose_bf16_kernel<<<dim3(16, 16, NLz), tb, 0, stream>>>(Wk, wqkvT, Dz, Dz, (long)Dz*Dz, (long)1536*Dz, 512);
    transpose_bf16_kernel<<<dim3(16, 16, NLz), tb, 0, stream>>>(Wv, wqkvT, Dz, Dz, (long)Dz*Dz, (long)1536*Dz, 1024);
    transpose_bf16_kernel<<<dim3(16, 16, NLz), tb, 0, stream>>>(Wo, woT, Dz, Dz, (long)Dz*Dz, (long)Dz*Dz, 0);
    transpose_bf16_kernel<<<dim3(64, 16, NLz), tb, 0, stream>>>(w1, w1T, Dz, DFz, (long)Dz*DFz, (long)DFz*Dz, 0);
    transpose_bf16_kernel<<<dim3(16, 64, NLz), tb, 0, stream>>>(w2, w2T, DFz, Dz, (long)DFz*Dz, (long)Dz*DFz, 0);

    posadd_kernel<<<dim3(Mz * Dz / 256), tb, 0, stream>>>(x_in, x_work);

    for (int lyr = 0; lyr < NLz; lyr++) {
        const short* wqkvL = wqkvT + (size_t)lyr * 1536 * Dz;
        const short* woL   = woT   + (size_t)lyr * Dz * Dz;
        const short* w1L   = w1T   + (size_t)lyr * DFz * Dz;
        const short* w2L   = w2T   + (size_t)lyr * Dz * DFz;

        ln_kernel<<<dim3(Mz), tb, 0, stream>>>(x_work, ln1g + lyr * Dz, ln1b + lyr * Dz, hbuf);
        gemm_bt<0><<<dim3(Mz/128, 1536/128), tb, 0, stream>>>(hbuf, wqkvL, qkvb, nullptr, nullptr, Mz, 1536, Dz);
        attn_kernel<<<dim3(Lz/64, Bz*Hz), tb, 0, stream>>>(qkvb, lengths, hbuf);
        gemm_bt<1><<<dim3(Mz/128, Dz/128), tb, 0, stream>>>(hbuf, woL, nullptr, x_work, nullptr, Mz, Dz, Dz);
        ln_kernel<<<dim3(Mz), tb, 0, stream>>>(x_work, ln2g + lyr * Dz, ln2b + lyr * Dz, hbuf);
        gemm_bt<2><<<dim3(Mz/128, DFz/128), tb, 0, stream>>>(hbuf, w1L, f1b, nullptr, b1 + lyr * DFz, Mz, DFz, Dz);
        gemm_bt<3><<<dim3(Mz/128, Dz/128), tb, 0, stream>>>(f1b, w2L, nullptr, x_work, b2 + lyr * Dz, Mz, Dz, DFz);
    }

    hipMemcpyAsync(d_out, x_work, (size_t)Mz * Dz * 4, hipMemcpyDeviceToDevice, stream);
}

// Round 2
// 1343.412 us; speedup vs baseline: 1.0857x; 1.0857x over previous
//
#include <hip/hip_runtime.h>
#include <cstdint>
#include <cstddef>

// ---- constants ----
#define Bz 8
#define Lz 1024
#define Dz 512
#define Hz 8
#define NLz 6
#define DFz 2048
#define Mz (Bz*Lz)          // 8192 rows

typedef short bf16x8 __attribute__((ext_vector_type(8)));
typedef float f32x4  __attribute__((ext_vector_type(4)));

__device__ __forceinline__ short f2bf(float f) {
    unsigned u = __builtin_bit_cast(unsigned, f);
    u = (u + 0x7fff + ((u >> 16) & 1)) >> 16;
    return (short)u;
}

__device__ __forceinline__ float exp2_fast(float x) {
#if __has_builtin(__builtin_amdgcn_exp2f)
    return __builtin_amdgcn_exp2f(x);
#else
    return exp2f(x);
#endif
}

#define GLD16(gp, lp) __builtin_amdgcn_global_load_lds( \
    (const __attribute__((address_space(1))) void*)(gp), \
    (__attribute__((address_space(3))) void*)(lp), 16, 0, 0)

// ---------------- pos-emb add:  y = x + PE  ----------------
__global__ __launch_bounds__(256) void posadd_kernel(const float* __restrict__ x,
                                                     float* __restrict__ y) {
    int idx = blockIdx.x * 256 + threadIdx.x;       // < B*L*D
    int d   = idx & (Dz - 1);
    int pos = (idx >> 9) & (Lz - 1);
    int i2  = (d < Dz/2) ? d : d - Dz/2;
    float inv = __expf(-0.03597789207f * (float)i2);   // 10000^(-2i/D)
    float a = (float)pos * inv;
    float pe = (d < Dz/2) ? sinf(a) : cosf(a);
    y[idx] = x[idx] + pe;
}

// ---------------- LayerNorm (f32 in, bf16 out), one row per block ----------------
__global__ __launch_bounds__(256) void ln_kernel(const float* __restrict__ x,
                                                 const float* __restrict__ g,
                                                 const float* __restrict__ b,
                                                 short* __restrict__ out) {
    int row = blockIdx.x;
    int t = threadIdx.x;
    const float* xr = x + (size_t)row * Dz;
    float v0 = xr[t], v1 = xr[t + 256];
    float s = v0 + v1;
    #pragma unroll
    for (int off = 32; off; off >>= 1) s += __shfl_xor(s, off, 64);
    __shared__ float red[4];
    int w = t >> 6, l = t & 63;
    if (l == 0) red[w] = s;
    __syncthreads();
    float m = (red[0] + red[1] + red[2] + red[3]) * (1.0f / Dz);
    float d0 = v0 - m, d1 = v1 - m;
    float s2 = d0 * d0 + d1 * d1;
    #pragma unroll
    for (int off = 32; off; off >>= 1) s2 += __shfl_xor(s2, off, 64);
    __syncthreads();
    if (l == 0) red[w] = s2;
    __syncthreads();
    float var = (red[0] + red[1] + red[2] + red[3]) * (1.0f / Dz);
    float rs = rsqrtf(var + 1e-3f);
    out[(size_t)row * Dz + t]       = f2bf(d0 * rs * g[t] + b[t]);
    out[(size_t)row * Dz + t + 256] = f2bf(d1 * rs * g[t + 256] + b[t + 256]);
}

// ---------------- weight transpose + cast: dst[n][k] = bf16(src[k][n]), batched over layers -------
__global__ __launch_bounds__(256) void transpose_bf16_kernel(const float* __restrict__ src,
                                                             short* __restrict__ dst,
                                                             int K, int N,
                                                             long srcLS, long dstLS, int rowOff) {
    __shared__ float tile[32][33];
    int tx = threadIdx.x & 31, ty = threadIdx.x >> 5;
    int bx = blockIdx.x, by = blockIdx.y, z = blockIdx.z;
    const float* s = src + (size_t)z * srcLS;
    short* d = dst + (size_t)z * dstLS;
    #pragma unroll
    for (int i = 0; i < 4; i++)
        tile[ty + i * 8][tx] = s[(size_t)(by * 32 + ty + i * 8) * N + bx * 32 + tx];
    __syncthreads();
    #pragma unroll
    for (int i = 0; i < 4; i++)
        d[(size_t)(rowOff + bx * 32 + ty + i * 8) * K + by * 32 + tx] = f2bf(tile[tx][ty + i * 8]);
}

// ---------------- V transpose: qkv[b*L+l][1024 + h*64 + d] -> vbt[(b*8+h)*64 + d][l] ------------
__global__ __launch_bounds__(256) void vtrans_kernel(const short* __restrict__ qkv,
                                                     short* __restrict__ vbt) {
    int lt = blockIdx.x, bh = blockIdx.y;
    int b = bh >> 3, h = bh & 7;
    __shared__ short tile[64][72];
    int t = threadIdx.x;
    int l = t >> 2, c4 = t & 3;
    #pragma unroll
    for (int p = 0; p < 2; p++) {
        int dd = (c4 + p * 4) * 8;
        *(uint4*)&tile[l][dd] =
            *(const uint4*)(qkv + ((size_t)(b * Lz + lt * 64 + l)) * 1536 + 1024 + h * 64 + dd);
    }
    __syncthreads();
    int d = t >> 2;
    #pragma unroll
    for (int p = 0; p < 2; p++) {
        int lc = (c4 + p * 4) * 8;
        union { uint4 u; short s[8]; } o;
        #pragma unroll
        for (int j = 0; j < 8; j++) o.s[j] = tile[lc + j][d];
        *(uint4*)(vbt + ((size_t)(bh * 64 + d)) * Lz + lt * 64 + lc) = o.u;
    }
}

// ---------------- GEMM: C[M,N] = A[M,K] * W[K,N], W given transposed (Bt[N][K]), bf16 in, f32 acc
// MODE 0: out bf16 (no bias)            -> outb
// MODE 1: outf[idx] += acc              (residual in-place, f32)
// MODE 2: out bf16 = relu(acc + bias)   -> outb
// MODE 3: outf[idx] += acc + bias       (residual in-place, f32)
template<int MODE>
__global__ __launch_bounds__(256, 2) void gemm_bt(const short* __restrict__ A,
                                                  const short* __restrict__ Bt,
                                                  short* __restrict__ outb,
                                                  float* __restrict__ outf,
                                                  const float* __restrict__ bias,
                                                  int M, int N, int K) {
    __shared__ __attribute__((aligned(16))) short As[128 * 32];
    __shared__ __attribute__((aligned(16))) short Bs[128 * 32];
    int t = threadIdx.x;
    int m0 = blockIdx.x * 128, n0 = blockIdx.y * 128;
    int w = t >> 6, l = t & 63;
    int wm = (w >> 1) * 64, wn = (w & 1) * 64;
    int lr = l & 15, lq = l >> 4;
    f32x4 acc[4][4] = {};
    int e0 = t, e1 = t + 256;
    int ra0 = e0 >> 2, ca0 = (e0 & 3) * 8;
    int ra1 = e1 >> 2, ca1 = (e1 & 3) * 8;
    for (int kk = 0; kk < K; kk += 32) {
        GLD16(A + (size_t)(m0 + ra0) * K + kk + ca0, As + e0 * 8);
        GLD16(A + (size_t)(m0 + ra1) * K + kk + ca1, As + e1 * 8);
        GLD16(Bt + (size_t)(n0 + ra0) * K + kk + ca0, Bs + e0 * 8);
        GLD16(Bt + (size_t)(n0 + ra1) * K + kk + ca1, Bs + e1 * 8);
        __syncthreads();
        bf16x8 af[4], bfr[4];
        #pragma unroll
        for (int i = 0; i < 4; i++) af[i]  = *(const bf16x8*)(As + (wm + i * 16 + lr) * 32 + lq * 8);
        #pragma unroll
        for (int i = 0; i < 4; i++) bfr[i] = *(const bf16x8*)(Bs + (wn + i * 16 + lr) * 32 + lq * 8);
        #pragma unroll
        for (int mi = 0; mi < 4; mi++)
            #pragma unroll
            for (int ni = 0; ni < 4; ni++)
                acc[mi][ni] = __builtin_amdgcn_mfma_f32_16x16x32_bf16(af[mi], bfr[ni], acc[mi][ni], 0, 0, 0);
        __syncthreads();
    }
    #pragma unroll
    for (int mi = 0; mi < 4; mi++)
        #pragma unroll
        for (int ni = 0; ni < 4; ni++) {
            int col = n0 + wn + ni * 16 + lr;
            float bv = (MODE == 2 || MODE == 3) ? bias[col] : 0.0f;
            #pragma unroll
            for (int r = 0; r < 4; r++) {
                int row = m0 + wm + mi * 16 + lq * 4 + r;
                size_t idx = (size_t)row * N + col;
                float v = acc[mi][ni][r];
                if (MODE == 0)      outb[idx] = f2bf(v);
                else if (MODE == 1) outf[idx] += v;
                else if (MODE == 2) outb[idx] = f2bf(fmaxf(v + bv, 0.0f));
                else                outf[idx] += v + bv;
            }
        }
}

// ---------------- fused attention, 128-key tiles, pipelined, online softmax ----------------
// qkv: [M][1536] bf16 (q|k|v);  vbt: [(b*8+h)*64 + d][L] bf16;  o: [M][512] bf16
// LDS: KP = K tile [128][72-pad]  ALIASED with per-wave P [16][136-pad];  Vs = V^T tile [64][136-pad]
__global__ __launch_bounds__(256, 4) void attn_kernel(const short* __restrict__ qkv,
                                                      const short* __restrict__ vbt,
                                                      const int* __restrict__ lengths,
                                                      short* __restrict__ o) {
    __shared__ __attribute__((aligned(16))) short KP[9216];     // 18432 B (K 128x72 / P 4x2304)
    __shared__ __attribute__((aligned(16))) short Vs[64 * 136]; // 17408 B
    int qt = blockIdx.x;            // q-tile of 64 rows
    int bh = blockIdx.y;
    int b = bh >> 3, h = bh & 7;
    int len = lengths[b];
    int t = threadIdx.x, w = t >> 6, l = t & 63;
    int lr = l & 15, lq = l >> 4;

    // Q fragments (A-layout: m=lr row, k=lq*8+j)
    const short* qrow = qkv + (size_t)(b * Lz + qt * 64 + w * 16 + lr) * 1536 + h * 64 + lq * 8;
    bf16x8 qf0 = *(const bf16x8*)(qrow);
    bf16x8 qf1 = *(const bf16x8*)(qrow + 32);

    // staging lane mapping
    int kkey = t >> 3, kd8 = (t & 7) * 8;      // K: key row within 32-group, d-offset
    int vd = t >> 4, vk8 = (t & 15) * 8;       // V: d row within 16-group, key-offset
    const short* kbaseg = qkv + (size_t)(b * Lz) * 1536 + 512 + h * 64;
    const short* vbaseg = vbt + (size_t)(bh * 64) * Lz;

    float mrun[4] = {-1e30f, -1e30f, -1e30f, -1e30f};
    float lrun[4] = {0.f, 0.f, 0.f, 0.f};
    f32x4 oacc[4] = {};
    const float SC2 = 0.18033688f;            // (1/8) * log2(e)
    bf16x8 onesf = {0x3F80, 0x3F80, 0x3F80, 0x3F80, 0x3F80, 0x3F80, 0x3F80, 0x3F80};

    uint4 kreg[4], vreg[4];
    #pragma unroll
    for (int i = 0; i < 4; i++)
        kreg[i] = *(const uint4*)(kbaseg + (size_t)(i * 32 + kkey) * 1536 + kd8);

    int ntiles = (len + 127) >> 7;
    for (int tix = 0; tix < ntiles; tix++) {
        int k0 = tix << 7;
        __syncthreads();                       // [A] prev-tile P/V reads complete
        #pragma unroll
        for (int i = 0; i < 4; i++)
            *(uint4*)(KP + (i * 32 + kkey) * 72 + kd8) = kreg[i];
        __syncthreads();                       // [B] K staged
        // V global loads for current tile (latency hidden under QK MFMAs)
        #pragma unroll
        for (int i = 0; i < 4; i++)
            vreg[i] = *(const uint4*)(vbaseg + (size_t)(i * 16 + vd) * Lz + k0 + vk8);
        // QK^T
        f32x4 sacc[8] = {};
        #pragma unroll
        for (int kt = 0; kt < 8; kt++) {
            bf16x8 kf0 = *(const bf16x8*)(KP + (kt * 16 + lr) * 72 + lq * 8);
            bf16x8 kf1 = *(const bf16x8*)(KP + (kt * 16 + lr) * 72 + 32 + lq * 8);
            sacc[kt] = __builtin_amdgcn_mfma_f32_16x16x32_bf16(qf0, kf0, sacc[kt], 0, 0, 0);
            sacc[kt] = __builtin_amdgcn_mfma_f32_16x16x32_bf16(qf1, kf1, sacc[kt], 0, 0, 0);
        }
        // K prefetch for next tile
        if (tix + 1 < ntiles) {
            #pragma unroll
            for (int i = 0; i < 4; i++)
                kreg[i] = *(const uint4*)(kbaseg + (size_t)(k0 + 128 + i * 32 + kkey) * 1536 + kd8);
        }
        // V stage into LDS
        #pragma unroll
        for (int i = 0; i < 4; i++)
            *(uint4*)(Vs + (i * 16 + vd) * 136 + vk8) = vreg[i];
        __syncthreads();                       // [C] all QK reads of KP done; V staged
        // softmax (exp2 domain)
        float biask[8];
        #pragma unroll
        for (int kt = 0; kt < 8; kt++)
            biask[kt] = ((k0 + kt * 16 + lr) < len) ? 0.0f : -1e30f;
        float p[8][4];
        #pragma unroll
        for (int r = 0; r < 4; r++) {
            float mx = -1e30f;
            #pragma unroll
            for (int kt = 0; kt < 8; kt++) {
                p[kt][r] = sacc[kt][r] * SC2 + biask[kt];
                mx = fmaxf(mx, p[kt][r]);
            }
            mx = fmaxf(mx, __shfl_xor(mx, 1, 64));
            mx = fmaxf(mx, __shfl_xor(mx, 2, 64));
            mx = fmaxf(mx, __shfl_xor(mx, 4, 64));
            mx = fmaxf(mx, __shfl_xor(mx, 8, 64));
            float mn = fmaxf(mrun[r], mx);
            float alpha = exp2_fast(mrun[r] - mn);
            mrun[r] = mn;
            #pragma unroll
            for (int kt = 0; kt < 8; kt++)
                p[kt][r] = exp2_fast(p[kt][r] - mn);
            lrun[r] *= alpha;
            #pragma unroll
            for (int ni = 0; ni < 4; ni++) oacc[ni][r] *= alpha;
        }
        // P -> LDS (wave-private region aliasing KP)
        short* Pw = KP + w * 2304;
        #pragma unroll
        for (int kt = 0; kt < 8; kt++)
            #pragma unroll
            for (int r = 0; r < 4; r++)
                Pw[(lq * 4 + r) * 136 + kt * 16 + lr] = f2bf(p[kt][r]);
        // PV (+ row-sum via ones-fragment MFMA)
        f32x4 sums = {};
        #pragma unroll
        for (int c = 0; c < 4; c++) {
            bf16x8 pf = *(const bf16x8*)(Pw + lr * 136 + c * 32 + lq * 8);
            sums = __builtin_amdgcn_mfma_f32_16x16x32_bf16(pf, onesf, sums, 0, 0, 0);
            #pragma unroll
            for (int ni = 0; ni < 4; ni++) {
                bf16x8 vf = *(const bf16x8*)(Vs + (ni * 16 + lr) * 136 + c * 32 + lq * 8);
                oacc[ni] = __builtin_amdgcn_mfma_f32_16x16x32_bf16(pf, vf, oacc[ni], 0, 0, 0);
            }
        }
        #pragma unroll
        for (int r = 0; r < 4; r++) lrun[r] += sums[r];
    }
    float inv_[4];
    #pragma unroll
    for (int r = 0; r < 4; r++) inv_[r] = 1.0f / lrun[r];
    #pragma unroll
    for (int ni = 0; ni < 4; ni++)
        #pragma unroll
        for (int r = 0; r < 4; r++) {
            int q = qt * 64 + w * 16 + lq * 4 + r;
            o[(size_t)(b * Lz + q) * Dz + h * 64 + ni * 16 + lr] = f2bf(oacc[ni][r] * inv_[r]);
        }
}

extern "C" void kernel_launch(void* const* d_in, const int* in_sizes, int n_in,
                              void* d_out, int out_size, void* d_ws, size_t ws_size,
                              hipStream_t stream) {
    const float* x_in    = (const float*)d_in[0];
    const int*   lengths = (const int*)d_in[1];
    const float* Wq   = (const float*)d_in[2];
    const float* Wk   = (const float*)d_in[3];
    const float* Wv   = (const float*)d_in[4];
    const float* Wo   = (const float*)d_in[5];
    const float* ln1g = (const float*)d_in[6];
    const float* ln1b = (const float*)d_in[7];
    const float* ln2g = (const float*)d_in[8];
    const float* ln2b = (const float*)d_in[9];
    const float* w1   = (const float*)d_in[10];
    const float* b1   = (const float*)d_in[11];
    const float* w2   = (const float*)d_in[12];
    const float* b2   = (const float*)d_in[13];

    size_t off = 0;
    auto alloc = [&](size_t bytes) {
        void* p = (char*)d_ws + off;
        off += (bytes + 255) & ~(size_t)255;
        return p;
    };
    float* x_work = (float*)alloc((size_t)Mz * Dz * 4);
    short* hbuf   = (short*)alloc((size_t)Mz * Dz * 2);        // LN out / attention out
    short* qkvb   = (short*)alloc((size_t)Mz * 1536 * 2);
    short* f1b    = (short*)alloc((size_t)Mz * DFz * 2);
    short* vbt    = (short*)alloc((size_t)Bz * Hz * 64 * Lz * 2);
    short* wqkvT  = (short*)alloc((size_t)NLz * 1536 * Dz * 2);
    short* woT    = (short*)alloc((size_t)NLz * Dz * Dz * 2);
    short* w1T    = (short*)alloc((size_t)NLz * DFz * Dz * 2);
    short* w2T    = (short*)alloc((size_t)NLz * Dz * DFz * 2);

    dim3 tb(256);
    // weight transposes (per call; same work every call)
    transpose_bf16_kernel<<<dim3(16, 16, NLz), tb, 0, stream>>>(Wq, wqkvT, Dz, Dz, (long)Dz*Dz, (long)1536*Dz, 0);
    transpose_bf16_kernel<<<dim3(16, 16, NLz), tb, 0, stream>>>(Wk, wqkvT, Dz, Dz, (long)Dz*Dz, (long)1536*Dz, 512);
    transpose_bf16_kernel<<<dim3(16, 16, NLz), tb, 0, stream>>>(Wv, wqkvT, Dz, Dz, (long)Dz*Dz, (long)1536*Dz, 1024);
    transpose_bf16_kernel<<<dim3(16, 16, NLz), tb, 0, stream>>>(Wo, woT, Dz, Dz, (long)Dz*Dz, (long)Dz*Dz, 0);
    transpose_bf16_kernel<<<dim3(64, 16, NLz), tb, 0, stream>>>(w1, w1T, Dz, DFz, (long)Dz*DFz, (long)DFz*Dz, 0);
    transpose_bf16_kernel<<<dim3(16, 64, NLz), tb, 0, stream>>>(w2, w2T, DFz, Dz, (long)DFz*Dz, (long)Dz*DFz, 0);

    posadd_kernel<<<dim3(Mz * Dz / 256), tb, 0, stream>>>(x_in, x_work);

    for (int lyr = 0; lyr < NLz; lyr++) {
        const short* wqkvL = wqkvT + (size_t)lyr * 1536 * Dz;
        const short* woL   = woT   + (size_t)lyr * Dz * Dz;
        const short* w1L   = w1T   + (size_t)lyr * DFz * Dz;
        const short* w2L   = w2T   + (size_t)lyr * Dz * DFz;

        ln_kernel<<<dim3(Mz), tb, 0, stream>>>(x_work, ln1g + lyr * Dz, ln1b + lyr * Dz, hbuf);
        gemm_bt<0><<<dim3(Mz/128, 1536/128), tb, 0, stream>>>(hbuf, wqkvL, qkvb, nullptr, nullptr, Mz, 1536, Dz);
        vtrans_kernel<<<dim3(Lz/64, Bz*Hz), tb, 0, stream>>>(qkvb, vbt);
        attn_kernel<<<dim3(Lz/64, Bz*Hz), tb, 0, stream>>>(qkvb, vbt, lengths, hbuf);
        gemm_bt<1><<<dim3(Mz/128, Dz/128), tb, 0, stream>>>(hbuf, woL, nullptr, x_work, nullptr, Mz, Dz, Dz);
        ln_kernel<<<dim3(Mz), tb, 0, stream>>>(x_work, ln2g + lyr * Dz, ln2b + lyr * Dz, hbuf);
        gemm_bt<2><<<dim3(Mz/128, DFz/128), tb, 0, stream>>>(hbuf, w1L, f1b, nullptr, b1 + lyr * DFz, Mz, DFz, Dz);
        gemm_bt<3><<<dim3(Mz/128, Dz/128), tb, 0, stream>>>(f1b, w2L, nullptr, x_work, b2 + lyr * Dz, Mz, Dz, DFz);
    }

    hipMemcpyAsync(d_out, x_work, (size_t)Mz * Dz * 4, hipMemcpyDeviceToDevice, stream);
}

// Round 3
// 1201.902 us; speedup vs baseline: 1.2135x; 1.1177x over previous
//
#include <hip/hip_runtime.h>
#include <cstdint>
#include <cstddef>

// ---- constants ----
#define Bz 8
#define Lz 1024
#define Dz 512
#define Hz 8
#define NLz 6
#define DFz 2048
#define Mz (Bz*Lz)          // 8192 rows

typedef short bf16x8 __attribute__((ext_vector_type(8)));
typedef float f32x4  __attribute__((ext_vector_type(4)));

__device__ __forceinline__ short f2bf(float f) {
    unsigned u = __builtin_bit_cast(unsigned, f);
    u = (u + 0x7fff + ((u >> 16) & 1)) >> 16;
    return (short)u;
}

__device__ __forceinline__ float exp2_fast(float x) {
#if __has_builtin(__builtin_amdgcn_exp2f)
    return __builtin_amdgcn_exp2f(x);
#else
    return exp2f(x);
#endif
}

#define GLD16(gp, lp) __builtin_amdgcn_global_load_lds( \
    (const __attribute__((address_space(1))) void*)(gp), \
    (__attribute__((address_space(3))) void*)(lp), 16, 0, 0)

// ---------------- pos-emb add:  y = x + PE  ----------------
__global__ __launch_bounds__(256) void posadd_kernel(const float* __restrict__ x,
                                                     float* __restrict__ y) {
    int idx = blockIdx.x * 256 + threadIdx.x;       // < B*L*D
    int d   = idx & (Dz - 1);
    int pos = (idx >> 9) & (Lz - 1);
    int i2  = (d < Dz/2) ? d : d - Dz/2;
    float inv = __expf(-0.03597789207f * (float)i2);   // 10000^(-2i/D)
    float a = (float)pos * inv;
    float pe = (d < Dz/2) ? sinf(a) : cosf(a);
    y[idx] = x[idx] + pe;
}

// ---------------- LayerNorm (f32 in, bf16 out), one row per block ----------------
__global__ __launch_bounds__(256) void ln_kernel(const float* __restrict__ x,
                                                 const float* __restrict__ g,
                                                 const float* __restrict__ b,
                                                 short* __restrict__ out) {
    int row = blockIdx.x;
    int t = threadIdx.x;
    const float* xr = x + (size_t)row * Dz;
    float v0 = xr[t], v1 = xr[t + 256];
    float s = v0 + v1;
    #pragma unroll
    for (int off = 32; off; off >>= 1) s += __shfl_xor(s, off, 64);
    __shared__ float red[4];
    int w = t >> 6, l = t & 63;
    if (l == 0) red[w] = s;
    __syncthreads();
    float m = (red[0] + red[1] + red[2] + red[3]) * (1.0f / Dz);
    float d0 = v0 - m, d1 = v1 - m;
    float s2 = d0 * d0 + d1 * d1;
    #pragma unroll
    for (int off = 32; off; off >>= 1) s2 += __shfl_xor(s2, off, 64);
    __syncthreads();
    if (l == 0) red[w] = s2;
    __syncthreads();
    float var = (red[0] + red[1] + red[2] + red[3]) * (1.0f / Dz);
    float rs = rsqrtf(var + 1e-3f);
    out[(size_t)row * Dz + t]       = f2bf(d0 * rs * g[t] + b[t]);
    out[(size_t)row * Dz + t + 256] = f2bf(d1 * rs * g[t + 256] + b[t + 256]);
}

// ---------------- weight transpose + cast: dst[n][k] = bf16(src[k][n]), batched over layers -------
__global__ __launch_bounds__(256) void transpose_bf16_kernel(const float* __restrict__ src,
                                                             short* __restrict__ dst,
                                                             int K, int N,
                                                             long srcLS, long dstLS, int rowOff) {
    __shared__ float tile[32][33];
    int tx = threadIdx.x & 31, ty = threadIdx.x >> 5;
    int bx = blockIdx.x, by = blockIdx.y, z = blockIdx.z;
    const float* s = src + (size_t)z * srcLS;
    short* d = dst + (size_t)z * dstLS;
    #pragma unroll
    for (int i = 0; i < 4; i++)
        tile[ty + i * 8][tx] = s[(size_t)(by * 32 + ty + i * 8) * N + bx * 32 + tx];
    __syncthreads();
    #pragma unroll
    for (int i = 0; i < 4; i++)
        d[(size_t)(rowOff + bx * 32 + ty + i * 8) * K + by * 32 + tx] = f2bf(tile[tx][ty + i * 8]);
}

// ---------------- V transpose: qkv[b*L+l][1024 + h*64 + d] -> vbt[(b*8+h)*64 + d][l] ------------
__global__ __launch_bounds__(256) void vtrans_kernel(const short* __restrict__ qkv,
                                                     short* __restrict__ vbt) {
    int lt = blockIdx.x, bh = blockIdx.y;
    int b = bh >> 3, h = bh & 7;
    __shared__ short tile[64][72];
    int t = threadIdx.x;
    int l = t >> 2, c4 = t & 3;
    #pragma unroll
    for (int p = 0; p < 2; p++) {
        int dd = (c4 + p * 4) * 8;
        *(uint4*)&tile[l][dd] =
            *(const uint4*)(qkv + ((size_t)(b * Lz + lt * 64 + l)) * 1536 + 1024 + h * 64 + dd);
    }
    __syncthreads();
    int d = t >> 2;
    #pragma unroll
    for (int p = 0; p < 2; p++) {
        int lc = (c4 + p * 4) * 8;
        union { uint4 u; short s[8]; } o;
        #pragma unroll
        for (int j = 0; j < 8; j++) o.s[j] = tile[lc + j][d];
        *(uint4*)(vbt + ((size_t)(bh * 64 + d)) * Lz + lt * 64 + lc) = o.u;
    }
}

// ---------------- GEMM: C[M,N] = A[M,K] * W[K,N], W given transposed (Bt[N][K]), bf16 in, f32 acc
// Tile 128 x TN (TN = 128 or 64).  TN=64 doubles grid for small-N GEMMs (inter-block overlap).
// MODE 0: out bf16 (no bias)            -> outb
// MODE 1: outf[idx] += acc              (residual in-place, f32)
// MODE 2: out bf16 = relu(acc + bias)   -> outb
// MODE 3: outf[idx] += acc + bias       (residual in-place, f32)
template<int MODE, int TN>
__global__ __launch_bounds__(256, (TN == 64) ? 4 : 2)
void gemm_bt(const short* __restrict__ A,
             const short* __restrict__ Bt,
             short* __restrict__ outb,
             float* __restrict__ outf,
             const float* __restrict__ bias,
             int M, int N, int K) {
    constexpr int NI = TN / 32;          // 4 or 2
    __shared__ __attribute__((aligned(16))) short As[128 * 32];
    __shared__ __attribute__((aligned(16))) short Bs[TN * 32];
    int t = threadIdx.x;
    int m0 = blockIdx.x * 128, n0 = blockIdx.y * TN;
    int w = t >> 6, l = t & 63;
    int wm = (w >> 1) * 64, wn = (w & 1) * (TN / 2);
    int lr = l & 15, lq = l >> 4;
    f32x4 acc[4][NI] = {};
    int ra0 = t >> 2, ca0 = (t & 3) * 8;
    int ra1 = (t + 256) >> 2;
    for (int kk = 0; kk < K; kk += 32) {
        GLD16(A + (size_t)(m0 + ra0) * K + kk + ca0, As + t * 8);
        GLD16(A + (size_t)(m0 + ra1) * K + kk + ca0, As + (t + 256) * 8);
        GLD16(Bt + (size_t)(n0 + ra0) * K + kk + ca0, Bs + t * 8);
        if constexpr (TN == 128)
            GLD16(Bt + (size_t)(n0 + ra1) * K + kk + ca0, Bs + (t + 256) * 8);
        __syncthreads();
        bf16x8 af[4], bfr[NI];
        #pragma unroll
        for (int i = 0; i < 4; i++)  af[i]  = *(const bf16x8*)(As + (wm + i * 16 + lr) * 32 + lq * 8);
        #pragma unroll
        for (int i = 0; i < NI; i++) bfr[i] = *(const bf16x8*)(Bs + (wn + i * 16 + lr) * 32 + lq * 8);
        #pragma unroll
        for (int mi = 0; mi < 4; mi++)
            #pragma unroll
            for (int ni = 0; ni < NI; ni++)
                acc[mi][ni] = __builtin_amdgcn_mfma_f32_16x16x32_bf16(af[mi], bfr[ni], acc[mi][ni], 0, 0, 0);
        __syncthreads();
    }
    #pragma unroll
    for (int mi = 0; mi < 4; mi++)
        #pragma unroll
        for (int ni = 0; ni < NI; ni++) {
            int col = n0 + wn + ni * 16 + lr;
            float bv = (MODE == 2 || MODE == 3) ? bias[col] : 0.0f;
            #pragma unroll
            for (int r = 0; r < 4; r++) {
                int row = m0 + wm + mi * 16 + lq * 4 + r;
                size_t idx = (size_t)row * N + col;
                float v = acc[mi][ni][r];
                if (MODE == 0)      outb[idx] = f2bf(v);
                else if (MODE == 1) outf[idx] += v;
                else if (MODE == 2) outb[idx] = f2bf(fmaxf(v + bv, 0.0f));
                else                outf[idx] += v + bv;
            }
        }
}

// ---------------- attention fragment: softmax + P->LDS + PV ----------------
__device__ __forceinline__ void attn_frag(f32x4* sacc, const float* biask,
                                          float* mr, float* lsum, f32x4* oacc,
                                          short* Pw, const short* Vs,
                                          int lr, int lq, bf16x8 onesf) {
    const float SC2 = 0.18033688f;            // (1/8) * log2(e)
    float p[8][4];
    #pragma unroll
    for (int r = 0; r < 4; r++) {
        float mx = -1e30f;
        #pragma unroll
        for (int kt = 0; kt < 8; kt++) {
            p[kt][r] = sacc[kt][r] * SC2 + biask[kt];
            mx = fmaxf(mx, p[kt][r]);
        }
        mx = fmaxf(mx, __shfl_xor(mx, 1, 64));
        mx = fmaxf(mx, __shfl_xor(mx, 2, 64));
        mx = fmaxf(mx, __shfl_xor(mx, 4, 64));
        mx = fmaxf(mx, __shfl_xor(mx, 8, 64));
        float mn = fmaxf(mr[r], mx);
        float alpha = exp2_fast(mr[r] - mn);
        mr[r] = mn;
        #pragma unroll
        for (int kt = 0; kt < 8; kt++)
            p[kt][r] = exp2_fast(p[kt][r] - mn);
        lsum[r] *= alpha;
        #pragma unroll
        for (int ni = 0; ni < 4; ni++) oacc[ni][r] *= alpha;
    }
    #pragma unroll
    for (int kt = 0; kt < 8; kt++)
        #pragma unroll
        for (int r = 0; r < 4; r++)
            Pw[(lq * 4 + r) * 136 + kt * 16 + lr] = f2bf(p[kt][r]);
    f32x4 sums = {};
    #pragma unroll
    for (int c = 0; c < 4; c++) {
        bf16x8 pf = *(const bf16x8*)(Pw + lr * 136 + c * 32 + lq * 8);
        sums = __builtin_amdgcn_mfma_f32_16x16x32_bf16(pf, onesf, sums, 0, 0, 0);
        #pragma unroll
        for (int ni = 0; ni < 4; ni++) {
            bf16x8 vf = *(const bf16x8*)(Vs + (ni * 16 + lr) * 136 + c * 32 + lq * 8);
            oacc[ni] = __builtin_amdgcn_mfma_f32_16x16x32_bf16(pf, vf, oacc[ni], 0, 0, 0);
        }
    }
    #pragma unroll
    for (int r = 0; r < 4; r++) lsum[r] += sums[r];
}

// ---------------- fused attention, 128 q-rows x 128-key tiles, online softmax ----------------
// qkv: [M][1536] bf16 (q|k|v);  vbt: [(b*8+h)*64 + d][L] bf16;  o: [M][512] bf16
// Each wave: 32 q-rows (2 fragments of 16, processed sequentially per key-tile).
__global__ __launch_bounds__(256, 2) void attn_kernel(const short* __restrict__ qkv,
                                                      const short* __restrict__ vbt,
                                                      const int* __restrict__ lengths,
                                                      short* __restrict__ o) {
    __shared__ __attribute__((aligned(16))) short Ks[128 * 72];   // 18432 B
    __shared__ __attribute__((aligned(16))) short Vs[64 * 136];   // 17408 B
    __shared__ __attribute__((aligned(16))) short Ps[4][16 * 136];// 17408 B
    int qt = blockIdx.x;            // q-tile of 128 rows
    int bh = blockIdx.y;
    int b = bh >> 3, h = bh & 7;
    int len = lengths[b];
    int t = threadIdx.x, w = t >> 6, l = t & 63;
    int lr = l & 15, lq = l >> 4;

    const short* q0 = qkv + (size_t)(b * Lz + qt * 128 + w * 32 + lr) * 1536 + h * 64 + lq * 8;
    bf16x8 qf0a = *(const bf16x8*)(q0);
    bf16x8 qf0b = *(const bf16x8*)(q0 + 32);
    bf16x8 qf1a = *(const bf16x8*)(q0 + 16 * 1536);
    bf16x8 qf1b = *(const bf16x8*)(q0 + 16 * 1536 + 32);

    int kkey = t >> 3, kd8 = (t & 7) * 8;
    int vd = t >> 4, vk8 = (t & 15) * 8;
    const short* kbaseg = qkv + (size_t)(b * Lz) * 1536 + 512 + h * 64;
    const short* vbaseg = vbt + (size_t)(bh * 64) * Lz;

    float mr0[4] = {-1e30f, -1e30f, -1e30f, -1e30f}, ls0[4] = {0.f, 0.f, 0.f, 0.f};
    float mr1[4] = {-1e30f, -1e30f, -1e30f, -1e30f}, ls1[4] = {0.f, 0.f, 0.f, 0.f};
    f32x4 oacc0[4] = {}, oacc1[4] = {};
    bf16x8 onesf = {0x3F80, 0x3F80, 0x3F80, 0x3F80, 0x3F80, 0x3F80, 0x3F80, 0x3F80};

    uint4 kreg[4], vreg[4];
    #pragma unroll
    for (int i = 0; i < 4; i++)
        kreg[i] = *(const uint4*)(kbaseg + (size_t)(i * 32 + kkey) * 1536 + kd8);

    short* Pw = &Ps[w][0];
    int ntiles = (len + 127) >> 7;
    for (int tix = 0; tix < ntiles; tix++) {
        int k0 = tix << 7;
        __syncthreads();                       // [A] prev-tile Ks/Vs/P reads complete
        #pragma unroll
        for (int i = 0; i < 4; i++)
            *(uint4*)(Ks + (i * 32 + kkey) * 72 + kd8) = kreg[i];
        __syncthreads();                       // [B] K staged
        // V global loads for current tile (hidden under QK MFMAs)
        #pragma unroll
        for (int i = 0; i < 4; i++)
            vreg[i] = *(const uint4*)(vbaseg + (size_t)(i * 16 + vd) * Lz + k0 + vk8);
        // QK^T fragment 0
        f32x4 sacc[8] = {};
        #pragma unroll
        for (int kt = 0; kt < 8; kt++) {
            bf16x8 kf0 = *(const bf16x8*)(Ks + (kt * 16 + lr) * 72 + lq * 8);
            bf16x8 kf1 = *(const bf16x8*)(Ks + (kt * 16 + lr) * 72 + 32 + lq * 8);
            sacc[kt] = __builtin_amdgcn_mfma_f32_16x16x32_bf16(qf0a, kf0, sacc[kt], 0, 0, 0);
            sacc[kt] = __builtin_amdgcn_mfma_f32_16x16x32_bf16(qf0b, kf1, sacc[kt], 0, 0, 0);
        }
        // K prefetch for next tile
        if (tix + 1 < ntiles) {
            #pragma unroll
            for (int i = 0; i < 4; i++)
                kreg[i] = *(const uint4*)(kbaseg + (size_t)(k0 + 128 + i * 32 + kkey) * 1536 + kd8);
        }
        // V stage into LDS
        #pragma unroll
        for (int i = 0; i < 4; i++)
            *(uint4*)(Vs + (i * 16 + vd) * 136 + vk8) = vreg[i];
        float biask[8];
        #pragma unroll
        for (int kt = 0; kt < 8; kt++)
            biask[kt] = ((k0 + kt * 16 + lr) < len) ? 0.0f : -1e30f;
        __syncthreads();                       // [C] Vs staged; Ks stays valid until next [A]
        // fragment 0: softmax + P + PV
        attn_frag(sacc, biask, mr0, ls0, oacc0, Pw, Vs, lr, lq, onesf);
        // QK^T fragment 1 (Ks still resident)
        #pragma unroll
        for (int kt = 0; kt < 8; kt++) {
            bf16x8 kf0 = *(const bf16x8*)(Ks + (kt * 16 + lr) * 72 + lq * 8);
            bf16x8 kf1 = *(const bf16x8*)(Ks + (kt * 16 + lr) * 72 + 32 + lq * 8);
            f32x4 s2 = {};
            s2 = __builtin_amdgcn_mfma_f32_16x16x32_bf16(qf1a, kf0, s2, 0, 0, 0);
            s2 = __builtin_amdgcn_mfma_f32_16x16x32_bf16(qf1b, kf1, s2, 0, 0, 0);
            sacc[kt] = s2;
        }
        attn_frag(sacc, biask, mr1, ls1, oacc1, Pw, Vs, lr, lq, onesf);
    }
    #pragma unroll
    for (int ni = 0; ni < 4; ni++)
        #pragma unroll
        for (int r = 0; r < 4; r++) {
            int q = qt * 128 + w * 32 + lq * 4 + r;
            size_t base = (size_t)(b * Lz + q) * Dz + h * 64 + ni * 16 + lr;
            o[base]             = f2bf(oacc0[ni][r] / ls0[r]);
            o[base + 16 * Dz]   = f2bf(oacc1[ni][r] / ls1[r]);
        }
}

extern "C" void kernel_launch(void* const* d_in, const int* in_sizes, int n_in,
                              void* d_out, int out_size, void* d_ws, size_t ws_size,
                              hipStream_t stream) {
    const float* x_in    = (const float*)d_in[0];
    const int*   lengths = (const int*)d_in[1];
    const float* Wq   = (const float*)d_in[2];
    const float* Wk   = (const float*)d_in[3];
    const float* Wv   = (const float*)d_in[4];
    const float* Wo   = (const float*)d_in[5];
    const float* ln1g = (const float*)d_in[6];
    const float* ln1b = (const float*)d_in[7];
    const float* ln2g = (const float*)d_in[8];
    const float* ln2b = (const float*)d_in[9];
    const float* w1   = (const float*)d_in[10];
    const float* b1   = (const float*)d_in[11];
    const float* w2   = (const float*)d_in[12];
    const float* b2   = (const float*)d_in[13];

    size_t off = 0;
    auto alloc = [&](size_t bytes) {
        void* p = (char*)d_ws + off;
        off += (bytes + 255) & ~(size_t)255;
        return p;
    };
    float* x_work = (float*)alloc((size_t)Mz * Dz * 4);
    short* hbuf   = (short*)alloc((size_t)Mz * Dz * 2);        // LN out / attention out
    short* qkvb   = (short*)alloc((size_t)Mz * 1536 * 2);
    short* f1b    = (short*)alloc((size_t)Mz * DFz * 2);
    short* vbt    = (short*)alloc((size_t)Bz * Hz * 64 * Lz * 2);
    short* wqkvT  = (short*)alloc((size_t)NLz * 1536 * Dz * 2);
    short* woT    = (short*)alloc((size_t)NLz * Dz * Dz * 2);
    short* w1T    = (short*)alloc((size_t)NLz * DFz * Dz * 2);
    short* w2T    = (short*)alloc((size_t)NLz * Dz * DFz * 2);

    dim3 tb(256);
    // weight transposes (per call; same work every call)
    transpose_bf16_kernel<<<dim3(16, 16, NLz), tb, 0, stream>>>(Wq, wqkvT, Dz, Dz, (long)Dz*Dz, (long)1536*Dz, 0);
    transpose_bf16_kernel<<<dim3(16, 16, NLz), tb, 0, stream>>>(Wk, wqkvT, Dz, Dz, (long)Dz*Dz, (long)1536*Dz, 512);
    transpose_bf16_kernel<<<dim3(16, 16, NLz), tb, 0, stream>>>(Wv, wqkvT, Dz, Dz, (long)Dz*Dz, (long)1536*Dz, 1024);
    transpose_bf16_kernel<<<dim3(16, 16, NLz), tb, 0, stream>>>(Wo, woT, Dz, Dz, (long)Dz*Dz, (long)Dz*Dz, 0);
    transpose_bf16_kernel<<<dim3(64, 16, NLz), tb, 0, stream>>>(w1, w1T, Dz, DFz, (long)Dz*DFz, (long)DFz*Dz, 0);
    transpose_bf16_kernel<<<dim3(16, 64, NLz), tb, 0, stream>>>(w2, w2T, DFz, Dz, (long)DFz*Dz, (long)Dz*DFz, 0);

    posadd_kernel<<<dim3(Mz * Dz / 256), tb, 0, stream>>>(x_in, x_work);

    for (int lyr = 0; lyr < NLz; lyr++) {
        const short* wqkvL = wqkvT + (size_t)lyr * 1536 * Dz;
        const short* woL   = woT   + (size_t)lyr * Dz * Dz;
        const short* w1L   = w1T   + (size_t)lyr * DFz * Dz;
        const short* w2L   = w2T   + (size_t)lyr * Dz * DFz;

        ln_kernel<<<dim3(Mz), tb, 0, stream>>>(x_work, ln1g + lyr * Dz, ln1b + lyr * Dz, hbuf);
        gemm_bt<0,128><<<dim3(Mz/128, 1536/128), tb, 0, stream>>>(hbuf, wqkvL, qkvb, nullptr, nullptr, Mz, 1536, Dz);
        vtrans_kernel<<<dim3(Lz/64, Bz*Hz), tb, 0, stream>>>(qkvb, vbt);
        attn_kernel<<<dim3(Lz/128, Bz*Hz), tb, 0, stream>>>(qkvb, vbt, lengths, hbuf);
        gemm_bt<1,64><<<dim3(Mz/128, Dz/64), tb, 0, stream>>>(hbuf, woL, nullptr, x_work, nullptr, Mz, Dz, Dz);
        ln_kernel<<<dim3(Mz), tb, 0, stream>>>(x_work, ln2g + lyr * Dz, ln2b + lyr * Dz, hbuf);
        gemm_bt<2,128><<<dim3(Mz/128, DFz/128), tb, 0, stream>>>(hbuf, w1L, f1b, nullptr, b1 + lyr * DFz, Mz, DFz, Dz);
        gemm_bt<3,64><<<dim3(Mz/128, Dz/64), tb, 0, stream>>>(f1b, w2L, nullptr, x_work, b2 + lyr * Dz, Mz, Dz, DFz);
    }

    hipMemcpyAsync(d_out, x_work, (size_t)Mz * Dz * 4, hipMemcpyDeviceToDevice, stream);
}